// Round 7
// baseline (401.912 us; speedup 1.0000x reference)
//
#include <hip/hip_runtime.h>
#include <hip/hip_bf16.h>

#define S_LEN 2048
#define D_MODEL 1024
#define NH 16
#define HDIM 64
#define B_SZ 4

typedef __attribute__((ext_vector_type(8))) short bf16x8;
typedef __attribute__((ext_vector_type(4))) float f32x4;

__device__ inline void gld16(const __hip_bfloat16* g, __hip_bfloat16* l) {
    __builtin_amdgcn_global_load_lds(
        (const __attribute__((address_space(1))) unsigned int*)g,
        (__attribute__((address_space(3))) unsigned int*)l, 16, 0, 0);
}

__device__ inline unsigned int pkbf(float a, float b) {
    float2 f; f.x = a; f.y = b;
    __hip_bfloat162 h = __float22bfloat162_rn(f);
    union { __hip_bfloat162 h; unsigned int u; } cv; cv.h = h; return cv.u;
}

// ---------------- fp32 -> bf16 convert (vectorized x4) ----------------
__global__ __launch_bounds__(256) void f2bf4_kernel(const float4* __restrict__ in,
                                                    __hip_bfloat162* __restrict__ out,
                                                    int n4) {
    int i = blockIdx.x * 256 + threadIdx.x;
    if (i < n4) {
        float4 v = in[i];
        __hip_bfloat162 a, b;
        a.x = __float2bfloat16(v.x); a.y = __float2bfloat16(v.y);
        b.x = __float2bfloat16(v.z); b.y = __float2bfloat16(v.w);
        out[2 * i]     = a;
        out[2 * i + 1] = b;
    }
}

// all four weight matrices in one launch (y picks the weight)
__global__ __launch_bounds__(256) void f2bfw_kernel(
    const float4* __restrict__ w0, const float4* __restrict__ w1,
    const float4* __restrict__ w2, const float4* __restrict__ w3,
    __hip_bfloat162* __restrict__ o0, __hip_bfloat162* __restrict__ o1,
    __hip_bfloat162* __restrict__ o2, __hip_bfloat162* __restrict__ o3) {
    const int z = blockIdx.y;
    const float4* in = (z == 0) ? w0 : (z == 1) ? w1 : (z == 2) ? w2 : w3;
    __hip_bfloat162* out = (z == 0) ? o0 : (z == 1) ? o1 : (z == 2) ? o2 : o3;
    int i = blockIdx.x * 256 + threadIdx.x;   // 262144 float4 per weight
    float4 v = in[i];
    __hip_bfloat162 a, b;
    a.x = __float2bfloat16(v.x); a.y = __float2bfloat16(v.y);
    b.x = __float2bfloat16(v.z); b.y = __float2bfloat16(v.w);
    out[2 * i]     = a;
    out[2 * i + 1] = b;
}

// ---------------- shared GEMM mainloop: C[128x128] = X[128xK] * W[128xK]^T ----
__device__ inline void gemm_mainloop(const __hip_bfloat16* __restrict__ X,
                                     const __hip_bfloat16* __restrict__ W,
                                     __hip_bfloat16* As, __hip_bfloat16* Bs,
                                     int m0, int n0, f32x4 acc[4][4]) {
    const int tid = threadIdx.x;
    const int wv = tid >> 6, lane = tid & 63, l15 = lane & 15, quad = lane >> 4;
    const int rw = (wv >> 1) * 64, cw = (wv & 1) * 64;
    for (int k0 = 0; k0 < D_MODEL; k0 += 32) {
        __syncthreads();
#pragma unroll
        for (int i = 0; i < 2; i++) {
            int l = tid + 256 * i;
            int row = l >> 2, c8 = (l & 3) * 8;
            gld16(&X[(size_t)(m0 + row) * D_MODEL + k0 + c8], &As[row * 32 + c8]);
            gld16(&W[(size_t)(n0 + row) * D_MODEL + k0 + c8], &Bs[row * 32 + c8]);
        }
        __syncthreads();
        bf16x8 af[4], bfr[4];
#pragma unroll
        for (int t = 0; t < 4; t++)
            af[t] = *(const bf16x8*)&As[(rw + t * 16 + l15) * 32 + quad * 8];
#pragma unroll
        for (int t = 0; t < 4; t++)
            bfr[t] = *(const bf16x8*)&Bs[(cw + t * 16 + l15) * 32 + quad * 8];
#pragma unroll
        for (int mt = 0; mt < 4; mt++)
#pragma unroll
            for (int nt = 0; nt < 4; nt++)
                acc[mt][nt] = __builtin_amdgcn_mfma_f32_16x16x32_bf16(
                    af[mt], bfr[nt], acc[mt][nt], 0, 0, 0);
    }
}

// ---------------- QKV projection + RoPE + scatter ---------------------------
// Q/K -> [B,H,S,hd] bf16 (Q pre-scaled by 1/8*log2e).
// V   -> TRANSPOSED [B,H,hd,S] bf16 so attention stages V^T like K (the
//        C-layout already gives each lane 4 consecutive s at fixed hd).
__global__ __launch_bounds__(256) void qkv_kernel(
    const __hip_bfloat16* __restrict__ X,
    const __hip_bfloat16* __restrict__ W0, const __hip_bfloat16* __restrict__ W1,
    const __hip_bfloat16* __restrict__ W2,
    const float* __restrict__ b0, const float* __restrict__ b1,
    const float* __restrict__ b2,
    const float* __restrict__ rc, const float* __restrict__ rs,
    __hip_bfloat16* __restrict__ Qo, __hip_bfloat16* __restrict__ Ko,
    __hip_bfloat16* __restrict__ Vo) {
    __shared__ __hip_bfloat16 As[128 * 32];
    __shared__ __hip_bfloat16 Bs[128 * 32];
    const int z = blockIdx.z;
    const __hip_bfloat16* W = (z == 0) ? W0 : ((z == 1) ? W1 : W2);
    const float* bias = (z == 0) ? b0 : ((z == 1) ? b1 : b2);
    f32x4 acc[4][4];
#pragma unroll
    for (int i = 0; i < 4; i++)
#pragma unroll
        for (int j = 0; j < 4; j++) acc[i][j] = (f32x4){0.f, 0.f, 0.f, 0.f};
    const int m0 = blockIdx.x * 128, n0 = blockIdx.y * 128;
    gemm_mainloop(X, W, As, Bs, m0, n0, acc);

    const int tid = threadIdx.x;
    const int wv = tid >> 6, lane = tid & 63, l15 = lane & 15, quad = lane >> 4;
    const int rw = (wv >> 1) * 64, cw = (wv & 1) * 64;

    if (z == 2) {
        // V^T write: lane holds s = mbase..mbase+3 at fixed hd -> one uint2
#pragma unroll
        for (int mt = 0; mt < 4; mt++) {
            int mbase = m0 + rw + mt * 16 + quad * 4;
            int s = mbase & (S_LEN - 1), b = mbase >> 11;
#pragma unroll
            for (int nt = 0; nt < 4; nt++) {
                int n = n0 + cw + nt * 16 + l15;
                int h = n >> 6, hd = n & 63;
                float bn = bias[n];
                uint2 st2;
                st2.x = pkbf(acc[mt][nt][0] + bn, acc[mt][nt][1] + bn);
                st2.y = pkbf(acc[mt][nt][2] + bn, acc[mt][nt][3] + bn);
                *(uint2*)&Vo[(((size_t)(b * NH + h)) * HDIM + hd) * S_LEN + s] = st2;
            }
        }
    } else {
        __hip_bfloat16* dst = (z == 0) ? Qo : Ko;
        const float qs = (z == 0) ? 0.18033688011112042f : 1.0f;  // 1/8*log2(e)
#pragma unroll
        for (int mt = 0; mt < 4; mt++)
#pragma unroll
            for (int r = 0; r < 4; r++) {
                int m = m0 + rw + mt * 16 + quad * 4 + r;
                int s = m & (S_LEN - 1), b = m >> 11;
#pragma unroll
                for (int nt = 0; nt < 2; nt++) {
                    int n1 = n0 + cw + nt * 16 + l15;
                    int h = n1 >> 6, hd1 = n1 & 63;  // hd1 in [0,32)
                    float y1 = acc[mt][nt][r] + bias[n1];
                    float y2 = acc[mt][nt + 2][r] + bias[n1 + 32];
                    float c1 = rc[s * HDIM + hd1], s1 = rs[s * HDIM + hd1];
                    float c2 = rc[s * HDIM + hd1 + 32], s2 = rs[s * HDIM + hd1 + 32];
                    size_t base = (((size_t)(b * NH + h)) * S_LEN + s) * HDIM;
                    dst[base + hd1]      = __float2bfloat16((y1 * c1 - y2 * s1) * qs);
                    dst[base + hd1 + 32] = __float2bfloat16((y2 * c2 + y1 * s2) * qs);
                }
            }
    }
}

// ---------------- flash attention, balanced causal pairing ------------------
// Block handles q-tiles tA=pr and tC=31-pr (64 q each): uniform 33 tile-
// updates/block. K and V^T staged identically (coalesced float4, K-pattern
// LDS stores — no 8-way transpose conflicts). S^T = K·Q^T, lane-scalar
// softmax (Q pre-scaled, no running max, diagonal mask in uniform branch).
// ctx^T = V^T·P^T with shuffle-built B-frags. Plain inline unrolled code
// (pointer-arg lambdas => scratch spills, round 4).
#define KP 72  // LDS pitch: 144B rows -> b128-aligned, 2-way-free banks
__global__ __launch_bounds__(256) void attn_kernel(
    const __hip_bfloat16* __restrict__ Q, const __hip_bfloat16* __restrict__ K,
    const __hip_bfloat16* __restrict__ V, __hip_bfloat16* __restrict__ CTX) {
    __shared__ __hip_bfloat16 Kl[2][64 * KP];
    __shared__ __hip_bfloat16 Vt[2][64 * KP];   // [dim][key], from global V^T
    const int tid = threadIdx.x;
    const int wv = tid >> 6, lane = tid & 63, l15 = lane & 15, quad = lane >> 4;
    const int bh = blockIdx.x;          // same-head blocks share an XCD (%8)
    const int pr = blockIdx.y;          // pair index 0..15
    const int tA = pr, tC = 31 - pr;
    const int nkb = tC + 1;
    const size_t off = (size_t)bh * S_LEN * HDIM;
    const __hip_bfloat16* Qp = Q + off;
    const __hip_bfloat16* Kp = K + off;
    const __hip_bfloat16* Vp = V + off;  // V^T: [hd][s], row stride S_LEN

    // Q fragments (B-operand of S^T MFMA)
    bf16x8 qfA[2], qfC[2];
#pragma unroll
    for (int c = 0; c < 2; c++) {
        qfA[c] = *(const bf16x8*)&Qp[(size_t)(tA * 64 + wv * 16 + l15) * HDIM + c * 32 + quad * 8];
        qfC[c] = *(const bf16x8*)&Qp[(size_t)(tC * 64 + wv * 16 + l15) * HDIM + c * 32 + quad * 8];
    }

    float lA = 0.f, lC = 0.f;
    f32x4 accA[4], accC[4];
#pragma unroll
    for (int nt = 0; nt < 4; nt++) {
        accA[nt] = (f32x4){0.f, 0.f, 0.f, 0.f};
        accC[nt] = (f32x4){0.f, 0.f, 0.f, 0.f};
    }

    float4 kreg[2], vreg[2];
    auto load_tile = [&](int kb) {
        const int k0 = kb * 64;
#pragma unroll
        for (int i = 0; i < 2; i++) {
            int l = tid + 256 * i;
            int row = l >> 3, col = (l & 7) * 8;
            kreg[i] = *(const float4*)&Kp[(size_t)(k0 + row) * HDIM + col];
            vreg[i] = *(const float4*)&Vp[(size_t)row * S_LEN + k0 + col];
        }
    };
    auto store_tile = [&](int buf) {
#pragma unroll
        for (int i = 0; i < 2; i++) {
            int l = tid + 256 * i;
            int row = l >> 3, col = (l & 7) * 8;
            *(float4*)&Kl[buf][row * KP + col] = kreg[i];
            *(float4*)&Vt[buf][row * KP + col] = vreg[i];
        }
    };

    const int srcA = l15 + ((quad & 1) << 5);
    const int srcB = srcA + 16;
    const bool hi = (quad >> 1) != 0;
    const int qrel = wv * 16 + l15;

    load_tile(0);
    for (int kb = 0; kb < nkb; kb++) {
        const int buf = kb & 1;
        store_tile(buf);
        __syncthreads();
        if (kb + 1 < nkb) load_tile(kb + 1);  // drains during compute

        const bool aAct = (kb <= tA);
        unsigned int pkC[8], pkA[8];

        // ---- tile C scores + softmax (always active) ----
        {
            f32x4 sa[4];
#pragma unroll
            for (int st = 0; st < 4; st++) sa[st] = (f32x4){0.f, 0.f, 0.f, 0.f};
#pragma unroll
            for (int c = 0; c < 2; c++)
#pragma unroll
                for (int st = 0; st < 4; st++) {
                    bf16x8 kf = *(const bf16x8*)&Kl[buf][(st * 16 + l15) * KP + c * 32 + quad * 8];
                    sa[st] = __builtin_amdgcn_mfma_f32_16x16x32_bf16(kf, qfC[c], sa[st], 0, 0, 0);
                }
            float ls = 0.f;
            if (kb == tC) {  // wave-uniform: only diagonal update pays mask cost
#pragma unroll
                for (int st = 0; st < 4; st++) {
                    float p[4];
#pragma unroll
                    for (int r = 0; r < 4; r++) {
                        bool msk = (st * 16 + quad * 4 + r > qrel);
                        p[r] = msk ? 0.f : __builtin_exp2f(sa[st][r]);
                        ls += p[r];
                    }
                    pkC[st * 2 + 0] = pkbf(p[0], p[1]);
                    pkC[st * 2 + 1] = pkbf(p[2], p[3]);
                }
            } else {
#pragma unroll
                for (int st = 0; st < 4; st++) {
                    float p[4];
#pragma unroll
                    for (int r = 0; r < 4; r++) {
                        p[r] = __builtin_exp2f(sa[st][r]);
                        ls += p[r];
                    }
                    pkC[st * 2 + 0] = pkbf(p[0], p[1]);
                    pkC[st * 2 + 1] = pkbf(p[2], p[3]);
                }
            }
            ls += __shfl_xor(ls, 16);
            ls += __shfl_xor(ls, 32);
            lC += ls;
        }
        // ---- tile A scores + softmax (active while kb <= tA) ----
        if (aAct) {
            f32x4 sa[4];
#pragma unroll
            for (int st = 0; st < 4; st++) sa[st] = (f32x4){0.f, 0.f, 0.f, 0.f};
#pragma unroll
            for (int c = 0; c < 2; c++)
#pragma unroll
                for (int st = 0; st < 4; st++) {
                    bf16x8 kf = *(const bf16x8*)&Kl[buf][(st * 16 + l15) * KP + c * 32 + quad * 8];
                    sa[st] = __builtin_amdgcn_mfma_f32_16x16x32_bf16(kf, qfA[c], sa[st], 0, 0, 0);
                }
            float ls = 0.f;
            if (kb == tA) {
#pragma unroll
                for (int st = 0; st < 4; st++) {
                    float p[4];
#pragma unroll
                    for (int r = 0; r < 4; r++) {
                        bool msk = (st * 16 + quad * 4 + r > qrel);
                        p[r] = msk ? 0.f : __builtin_exp2f(sa[st][r]);
                        ls += p[r];
                    }
                    pkA[st * 2 + 0] = pkbf(p[0], p[1]);
                    pkA[st * 2 + 1] = pkbf(p[2], p[3]);
                }
            } else {
#pragma unroll
                for (int st = 0; st < 4; st++) {
                    float p[4];
#pragma unroll
                    for (int r = 0; r < 4; r++) {
                        p[r] = __builtin_exp2f(sa[st][r]);
                        ls += p[r];
                    }
                    pkA[st * 2 + 0] = pkbf(p[0], p[1]);
                    pkA[st * 2 + 1] = pkbf(p[2], p[3]);
                }
            }
            ls += __shfl_xor(ls, 16);
            ls += __shfl_xor(ls, 32);
            lA += ls;
        }

        // ---- PV: ctx^T += V^T · P^T (shuffle-built P^T B-frags) ----
#pragma unroll
        for (int c = 0; c < 2; c++) {
            bf16x8 vf[4];
#pragma unroll
            for (int nt = 0; nt < 4; nt++)
                vf[nt] = *(const bf16x8*)&Vt[buf][(nt * 16 + l15) * KP + c * 32 + quad * 8];
            {
                unsigned int a0 = __shfl((int)pkC[4 * c + 0], srcA);
                unsigned int a1 = __shfl((int)pkC[4 * c + 1], srcA);
                unsigned int a2 = __shfl((int)pkC[4 * c + 0], srcB);
                unsigned int a3 = __shfl((int)pkC[4 * c + 1], srcB);
                unsigned int b0 = __shfl((int)pkC[4 * c + 2], srcA);
                unsigned int b1 = __shfl((int)pkC[4 * c + 3], srcA);
                unsigned int b2 = __shfl((int)pkC[4 * c + 2], srcB);
                unsigned int b3 = __shfl((int)pkC[4 * c + 3], srcB);
                union { unsigned int u[4]; bf16x8 v; } pf;
                pf.u[0] = hi ? b0 : a0;
                pf.u[1] = hi ? b1 : a1;
                pf.u[2] = hi ? b2 : a2;
                pf.u[3] = hi ? b3 : a3;
#pragma unroll
                for (int nt = 0; nt < 4; nt++)
                    accC[nt] = __builtin_amdgcn_mfma_f32_16x16x32_bf16(vf[nt], pf.v, accC[nt], 0, 0, 0);
            }
            if (aAct) {
                unsigned int a0 = __shfl((int)pkA[4 * c + 0], srcA);
                unsigned int a1 = __shfl((int)pkA[4 * c + 1], srcA);
                unsigned int a2 = __shfl((int)pkA[4 * c + 0], srcB);
                unsigned int a3 = __shfl((int)pkA[4 * c + 1], srcB);
                unsigned int b0 = __shfl((int)pkA[4 * c + 2], srcA);
                unsigned int b1 = __shfl((int)pkA[4 * c + 3], srcA);
                unsigned int b2 = __shfl((int)pkA[4 * c + 2], srcB);
                unsigned int b3 = __shfl((int)pkA[4 * c + 3], srcB);
                union { unsigned int u[4]; bf16x8 v; } pf;
                pf.u[0] = hi ? b0 : a0;
                pf.u[1] = hi ? b1 : a1;
                pf.u[2] = hi ? b2 : a2;
                pf.u[3] = hi ? b3 : a3;
#pragma unroll
                for (int nt = 0; nt < 4; nt++)
                    accA[nt] = __builtin_amdgcn_mfma_f32_16x16x32_bf16(vf[nt], pf.v, accA[nt], 0, 0, 0);
            }
        }
    }

    const int b = bh >> 4, h = bh & 15;
    {
        const int q = tA * 64 + wv * 16 + l15;
        const float inv = 1.0f / lA;
#pragma unroll
        for (int nt = 0; nt < 4; nt++) {
            uint2 st2;
            st2.x = pkbf(accA[nt][0] * inv, accA[nt][1] * inv);
            st2.y = pkbf(accA[nt][2] * inv, accA[nt][3] * inv);
            *(uint2*)&CTX[((size_t)(b * S_LEN + q)) * D_MODEL + h * HDIM + nt * 16 + quad * 4] = st2;
        }
    }
    {
        const int q = tC * 64 + wv * 16 + l15;
        const float inv = 1.0f / lC;
#pragma unroll
        for (int nt = 0; nt < 4; nt++) {
            uint2 st2;
            st2.x = pkbf(accC[nt][0] * inv, accC[nt][1] * inv);
            st2.y = pkbf(accC[nt][2] * inv, accC[nt][3] * inv);
            *(uint2*)&CTX[((size_t)(b * S_LEN + q)) * D_MODEL + h * HDIM + nt * 16 + quad * 4] = st2;
        }
    }
}

// ---------------- output projection: fp32 out = ctx @ Wo^T + bo --------------
__global__ __launch_bounds__(256) void outproj_kernel(
    const __hip_bfloat16* __restrict__ X, const __hip_bfloat16* __restrict__ W,
    const float* __restrict__ bias, float* __restrict__ OUT) {
    __shared__ __hip_bfloat16 As[128 * 32];
    __shared__ __hip_bfloat16 Bs[128 * 32];
    f32x4 acc[4][4];
#pragma unroll
    for (int i = 0; i < 4; i++)
#pragma unroll
        for (int j = 0; j < 4; j++) acc[i][j] = (f32x4){0.f, 0.f, 0.f, 0.f};
    const int m0 = blockIdx.x * 128, n0 = blockIdx.y * 128;
    gemm_mainloop(X, W, As, Bs, m0, n0, acc);
    const int tid = threadIdx.x;
    const int wv = tid >> 6, lane = tid & 63, l15 = lane & 15, quad = lane >> 4;
    const int rw = (wv >> 1) * 64, cw = (wv & 1) * 64;
#pragma unroll
    for (int mt = 0; mt < 4; mt++)
#pragma unroll
        for (int r = 0; r < 4; r++) {
            int m = m0 + rw + mt * 16 + quad * 4 + r;
#pragma unroll
            for (int nt = 0; nt < 4; nt++) {
                int n = n0 + cw + nt * 16 + l15;
                OUT[(size_t)m * D_MODEL + n] = acc[mt][nt][r] + bias[n];
            }
        }
}

extern "C" void kernel_launch(void* const* d_in, const int* in_sizes, int n_in,
                              void* d_out, int out_size, void* d_ws, size_t ws_size,
                              hipStream_t stream) {
    const float* x  = (const float*)d_in[0];
    const float* rc = (const float*)d_in[2];
    const float* rs = (const float*)d_in[3];
    const float* Wq = (const float*)d_in[4];
    const float* bq = (const float*)d_in[5];
    const float* Wk = (const float*)d_in[6];
    const float* bk = (const float*)d_in[7];
    const float* Wv = (const float*)d_in[8];
    const float* bv = (const float*)d_in[9];
    const float* Wo = (const float*)d_in[10];
    const float* bo = (const float*)d_in[11];

    char* ws = (char*)d_ws;
    __hip_bfloat16* xbf = (__hip_bfloat16*)(ws);                    // 16 MB
    __hip_bfloat16* wqb = (__hip_bfloat16*)(ws + (16u << 20));      // 2 MB
    __hip_bfloat16* wkb = (__hip_bfloat16*)(ws + (18u << 20));
    __hip_bfloat16* wvb = (__hip_bfloat16*)(ws + (20u << 20));
    __hip_bfloat16* wob = (__hip_bfloat16*)(ws + (22u << 20));
    __hip_bfloat16* Qb  = (__hip_bfloat16*)(ws + (24u << 20));      // 16 MB
    __hip_bfloat16* Kb  = (__hip_bfloat16*)(ws + (40u << 20));
    __hip_bfloat16* Vb  = (__hip_bfloat16*)(ws + (56u << 20));      // V^T [B,H,hd,S]
    __hip_bfloat16* Cb  = (__hip_bfloat16*)(ws + (72u << 20));      // 16 MB
    float* out = (float*)d_out;

    f2bf4_kernel<<<8192, 256, 0, stream>>>((const float4*)x, (__hip_bfloat162*)xbf, 2097152);
    f2bfw_kernel<<<dim3(1024, 4), 256, 0, stream>>>(
        (const float4*)Wq, (const float4*)Wk, (const float4*)Wv, (const float4*)Wo,
        (__hip_bfloat162*)wqb, (__hip_bfloat162*)wkb, (__hip_bfloat162*)wvb,
        (__hip_bfloat162*)wob);

    qkv_kernel<<<dim3(64, 8, 3), 256, 0, stream>>>(xbf, wqb, wkb, wvb, bq, bk, bv,
                                                   rc, rs, Qb, Kb, Vb);
    attn_kernel<<<dim3(64, 16), 256, 0, stream>>>(Qb, Kb, Vb, Cb);
    outproj_kernel<<<dim3(64, 8), 256, 0, stream>>>(Cb, wob, bo, out);
}

// Round 8
// 382.563 us; speedup vs baseline: 1.0506x; 1.0506x over previous
//
#include <hip/hip_runtime.h>
#include <hip/hip_bf16.h>

#define S_LEN 2048
#define D_MODEL 1024
#define NH 16
#define HDIM 64
#define B_SZ 4

typedef __attribute__((ext_vector_type(8))) short bf16x8;
typedef __attribute__((ext_vector_type(4))) float f32x4;

__device__ inline void gld16(const __hip_bfloat16* g, __hip_bfloat16* l) {
    __builtin_amdgcn_global_load_lds(
        (const __attribute__((address_space(1))) unsigned int*)g,
        (__attribute__((address_space(3))) unsigned int*)l, 16, 0, 0);
}

__device__ inline unsigned int pkbf(float a, float b) {
    float2 f; f.x = a; f.y = b;
    __hip_bfloat162 h = __float22bfloat162_rn(f);
    union { __hip_bfloat162 h; unsigned int u; } cv; cv.h = h; return cv.u;
}

// ---------------- fp32 -> bf16 convert (vectorized x4) ----------------
__global__ __launch_bounds__(256) void f2bf4_kernel(const float4* __restrict__ in,
                                                    __hip_bfloat162* __restrict__ out,
                                                    int n4) {
    int i = blockIdx.x * 256 + threadIdx.x;
    if (i < n4) {
        float4 v = in[i];
        __hip_bfloat162 a, b;
        a.x = __float2bfloat16(v.x); a.y = __float2bfloat16(v.y);
        b.x = __float2bfloat16(v.z); b.y = __float2bfloat16(v.w);
        out[2 * i]     = a;
        out[2 * i + 1] = b;
    }
}

// all four weight matrices in one launch (y picks the weight)
__global__ __launch_bounds__(256) void f2bfw_kernel(
    const float4* __restrict__ w0, const float4* __restrict__ w1,
    const float4* __restrict__ w2, const float4* __restrict__ w3,
    __hip_bfloat162* __restrict__ o0, __hip_bfloat162* __restrict__ o1,
    __hip_bfloat162* __restrict__ o2, __hip_bfloat162* __restrict__ o3) {
    const int z = blockIdx.y;
    const float4* in = (z == 0) ? w0 : (z == 1) ? w1 : (z == 2) ? w2 : w3;
    __hip_bfloat162* out = (z == 0) ? o0 : (z == 1) ? o1 : (z == 2) ? o2 : o3;
    int i = blockIdx.x * 256 + threadIdx.x;   // 262144 float4 per weight
    float4 v = in[i];
    __hip_bfloat162 a, b;
    a.x = __float2bfloat16(v.x); a.y = __float2bfloat16(v.y);
    b.x = __float2bfloat16(v.z); b.y = __float2bfloat16(v.w);
    out[2 * i]     = a;
    out[2 * i + 1] = b;
}

// ---------------- shared GEMM mainloop: C[128x128] = X[128xK] * W[128xK]^T ----
__device__ inline void gemm_mainloop(const __hip_bfloat16* __restrict__ X,
                                     const __hip_bfloat16* __restrict__ W,
                                     __hip_bfloat16* As, __hip_bfloat16* Bs,
                                     int m0, int n0, f32x4 acc[4][4]) {
    const int tid = threadIdx.x;
    const int wv = tid >> 6, lane = tid & 63, l15 = lane & 15, quad = lane >> 4;
    const int rw = (wv >> 1) * 64, cw = (wv & 1) * 64;
    for (int k0 = 0; k0 < D_MODEL; k0 += 32) {
        __syncthreads();
#pragma unroll
        for (int i = 0; i < 2; i++) {
            int l = tid + 256 * i;
            int row = l >> 2, c8 = (l & 3) * 8;
            gld16(&X[(size_t)(m0 + row) * D_MODEL + k0 + c8], &As[row * 32 + c8]);
            gld16(&W[(size_t)(n0 + row) * D_MODEL + k0 + c8], &Bs[row * 32 + c8]);
        }
        __syncthreads();
        bf16x8 af[4], bfr[4];
#pragma unroll
        for (int t = 0; t < 4; t++)
            af[t] = *(const bf16x8*)&As[(rw + t * 16 + l15) * 32 + quad * 8];
#pragma unroll
        for (int t = 0; t < 4; t++)
            bfr[t] = *(const bf16x8*)&Bs[(cw + t * 16 + l15) * 32 + quad * 8];
#pragma unroll
        for (int mt = 0; mt < 4; mt++)
#pragma unroll
            for (int nt = 0; nt < 4; nt++)
                acc[mt][nt] = __builtin_amdgcn_mfma_f32_16x16x32_bf16(
                    af[mt], bfr[nt], acc[mt][nt], 0, 0, 0);
    }
}

// ---------------- QKV projection + RoPE + scatter to [B,H,S,hd] bf16 ---------
// Q pre-scaled by 1/8*log2e so attention exp2 needs no multiply. (round-6
// epilogue: row-major packed writes — producer-side V^T scatter regressed
// both kernels via 32B partial-line RMW traffic, round 7.)
__global__ __launch_bounds__(256) void qkv_kernel(
    const __hip_bfloat16* __restrict__ X,
    const __hip_bfloat16* __restrict__ W0, const __hip_bfloat16* __restrict__ W1,
    const __hip_bfloat16* __restrict__ W2,
    const float* __restrict__ b0, const float* __restrict__ b1,
    const float* __restrict__ b2,
    const float* __restrict__ rc, const float* __restrict__ rs,
    __hip_bfloat16* __restrict__ Qo, __hip_bfloat16* __restrict__ Ko,
    __hip_bfloat16* __restrict__ Vo) {
    __shared__ __hip_bfloat16 As[128 * 32];
    __shared__ __hip_bfloat16 Bs[128 * 32];
    const int z = blockIdx.z;
    const __hip_bfloat16* W = (z == 0) ? W0 : ((z == 1) ? W1 : W2);
    const float* bias = (z == 0) ? b0 : ((z == 1) ? b1 : b2);
    f32x4 acc[4][4];
#pragma unroll
    for (int i = 0; i < 4; i++)
#pragma unroll
        for (int j = 0; j < 4; j++) acc[i][j] = (f32x4){0.f, 0.f, 0.f, 0.f};
    const int m0 = blockIdx.x * 128, n0 = blockIdx.y * 128;
    gemm_mainloop(X, W, As, Bs, m0, n0, acc);

    const int tid = threadIdx.x;
    const int wv = tid >> 6, lane = tid & 63, l15 = lane & 15, quad = lane >> 4;
    const int rw = (wv >> 1) * 64, cw = (wv & 1) * 64;

    if (z == 2) {
#pragma unroll
        for (int mt = 0; mt < 4; mt++)
#pragma unroll
            for (int r = 0; r < 4; r++) {
                int m = m0 + rw + mt * 16 + quad * 4 + r;
                int s = m & (S_LEN - 1), b = m >> 11;
#pragma unroll
                for (int nt = 0; nt < 4; nt++) {
                    int n = n0 + cw + nt * 16 + l15;
                    int h = n >> 6, hd = n & 63;
                    float v = acc[mt][nt][r] + bias[n];
                    Vo[(((size_t)(b * NH + h)) * S_LEN + s) * HDIM + hd] =
                        __float2bfloat16(v);
                }
            }
    } else {
        __hip_bfloat16* dst = (z == 0) ? Qo : Ko;
        const float qs = (z == 0) ? 0.18033688011112042f : 1.0f;  // 1/8*log2(e)
#pragma unroll
        for (int mt = 0; mt < 4; mt++)
#pragma unroll
            for (int r = 0; r < 4; r++) {
                int m = m0 + rw + mt * 16 + quad * 4 + r;
                int s = m & (S_LEN - 1), b = m >> 11;
#pragma unroll
                for (int nt = 0; nt < 2; nt++) {
                    int n1 = n0 + cw + nt * 16 + l15;
                    int h = n1 >> 6, hd1 = n1 & 63;  // hd1 in [0,32)
                    float y1 = acc[mt][nt][r] + bias[n1];
                    float y2 = acc[mt][nt + 2][r] + bias[n1 + 32];
                    float c1 = rc[s * HDIM + hd1], s1 = rs[s * HDIM + hd1];
                    float c2 = rc[s * HDIM + hd1 + 32], s2 = rs[s * HDIM + hd1 + 32];
                    size_t base = (((size_t)(b * NH + h)) * S_LEN + s) * HDIM;
                    dst[base + hd1]      = __float2bfloat16((y1 * c1 - y2 * s1) * qs);
                    dst[base + hd1 + 32] = __float2bfloat16((y2 * c2 + y1 * s2) * qs);
                }
            }
    }
}

// ---------------- V transpose: [B,H,S,hd] -> [B,H,hd,S], coalesced both sides
__global__ __launch_bounds__(256) void vt_kernel(
    const __hip_bfloat16* __restrict__ V, __hip_bfloat16* __restrict__ VT) {
    __shared__ __hip_bfloat162 T[64][33];   // [hd][s-pair], pad 33
    const int tid = threadIdx.x;
    const int bh = blockIdx.x, st = blockIdx.y;
    const size_t off = (size_t)bh * S_LEN * HDIM;
    const int s0 = st * 64;
    // load: thread -> s-pair a = tid>>3 (s=2a,2a+1), hd block = (tid&7)*8
    {
        const int a = tid >> 3, hb = (tid & 7) * 8;
        float4 f0 = *(const float4*)&V[off + (size_t)(s0 + 2 * a) * HDIM + hb];
        float4 f1 = *(const float4*)&V[off + (size_t)(s0 + 2 * a + 1) * HDIM + hb];
        union { float4 f; unsigned short u[8]; } u0, u1;
        u0.f = f0; u1.f = f1;
#pragma unroll
        for (int j = 0; j < 8; j++) {
            union { __hip_bfloat162 h; unsigned int u; } cv;
            cv.u = (unsigned int)u0.u[j] | ((unsigned int)u1.u[j] << 16);
            T[hb + j][a] = cv.h;
        }
    }
    __syncthreads();
    // store: thread -> hd = idx>>3, s block = (idx&7)*8 (4 bf162)
#pragma unroll
    for (int i = 0; i < 2; i++) {
        int idx = tid + 256 * i;
        int hd = idx >> 3, sb = idx & 7;
        union { float4 f; __hip_bfloat162 h[4]; } o;
#pragma unroll
        for (int k = 0; k < 4; k++) o.h[k] = T[hd][sb * 4 + k];
        *(float4*)&VT[off + (size_t)hd * S_LEN + s0 + sb * 8] = o.f;
    }
}

// ---------------- flash attention, single 64-q tile per block ---------------
// Grid (bh=64, 32 tiles), longest tiles dispatched first -> dynamic backfill
// balances causal work. K and V^T staged identically (coalesced float4).
// LDS: XOR-swizzled pitch-64 (rows 128B): stores, score reads and PV reads
// all hit 8 distinct 4-bank groups per 8 lanes -> <=2-way (free). 32 KB/block
// -> 5 blocks/CU. S^T = K*Q^T lane-scalar softmax (Q pre-scaled, no running
// max, diagonal mask in wave-uniform branch). ctx^T = V^T*P^T with shuffle-
// built B-frags. Plain inline code (pointer-arg lambdas => spills, round 4).
#define SWZ(row, blk) (((row) << 6) + (((blk) ^ ((row) & 7)) << 3))
__global__ __launch_bounds__(256) void attn_kernel(
    const __hip_bfloat16* __restrict__ Q, const __hip_bfloat16* __restrict__ K,
    const __hip_bfloat16* __restrict__ V, __hip_bfloat16* __restrict__ CTX) {
    __shared__ __hip_bfloat16 Kl[2][64 * 64];
    __shared__ __hip_bfloat16 Vt[2][64 * 64];   // [dim][key] from global V^T
    const int tid = threadIdx.x;
    const int wv = tid >> 6, lane = tid & 63, l15 = lane & 15, quad = lane >> 4;
    const int bh = blockIdx.x;          // same-head blocks share an XCD (%8)
    const int t = 31 - (int)blockIdx.y; // longest first
    const int nkb = t + 1;
    const size_t off = (size_t)bh * S_LEN * HDIM;
    const __hip_bfloat16* Qp = Q + off;
    const __hip_bfloat16* Kp = K + off;
    const __hip_bfloat16* Vp = V + off;  // V^T: [hd][s], row stride S_LEN

    bf16x8 qf[2];
#pragma unroll
    for (int c = 0; c < 2; c++)
        qf[c] = *(const bf16x8*)&Qp[(size_t)(t * 64 + wv * 16 + l15) * HDIM + c * 32 + quad * 8];

    float l_i = 0.f;
    f32x4 acc[4];
#pragma unroll
    for (int nt = 0; nt < 4; nt++) acc[nt] = (f32x4){0.f, 0.f, 0.f, 0.f};

    float4 kreg[2], vreg[2];
    auto load_tile = [&](int kb) {
        const int k0 = kb * 64;
#pragma unroll
        for (int i = 0; i < 2; i++) {
            int l = tid + 256 * i;
            int row = l >> 3, col = (l & 7) * 8;
            kreg[i] = *(const float4*)&Kp[(size_t)(k0 + row) * HDIM + col];
            vreg[i] = *(const float4*)&Vp[(size_t)row * S_LEN + k0 + col];
        }
    };
    auto store_tile = [&](int buf) {
#pragma unroll
        for (int i = 0; i < 2; i++) {
            int l = tid + 256 * i;
            int row = l >> 3, blk = l & 7;
            *(float4*)&Kl[buf][SWZ(row, blk)] = kreg[i];
            *(float4*)&Vt[buf][SWZ(row, blk)] = vreg[i];
        }
    };

    const int srcA = l15 + ((quad & 1) << 5);
    const int srcB = srcA + 16;
    const bool hi = (quad >> 1) != 0;
    const int qrel = wv * 16 + l15;

    load_tile(0);
    for (int kb = 0; kb < nkb; kb++) {
        const int buf = kb & 1;
        store_tile(buf);
        __syncthreads();
        if (kb + 1 < nkb) load_tile(kb + 1);  // drains during compute

        unsigned int pk[8];
        {
            f32x4 sa[4];
#pragma unroll
            for (int st = 0; st < 4; st++) sa[st] = (f32x4){0.f, 0.f, 0.f, 0.f};
#pragma unroll
            for (int c = 0; c < 2; c++)
#pragma unroll
                for (int st = 0; st < 4; st++) {
                    bf16x8 kf = *(const bf16x8*)&Kl[buf][SWZ(st * 16 + l15, 4 * c + quad)];
                    sa[st] = __builtin_amdgcn_mfma_f32_16x16x32_bf16(kf, qf[c], sa[st], 0, 0, 0);
                }
            float ls = 0.f;
            if (kb == t) {  // wave-uniform: only diagonal update pays mask cost
#pragma unroll
                for (int st = 0; st < 4; st++) {
                    float p[4];
#pragma unroll
                    for (int r = 0; r < 4; r++) {
                        bool msk = (st * 16 + quad * 4 + r > qrel);
                        p[r] = msk ? 0.f : __builtin_exp2f(sa[st][r]);
                        ls += p[r];
                    }
                    pk[st * 2 + 0] = pkbf(p[0], p[1]);
                    pk[st * 2 + 1] = pkbf(p[2], p[3]);
                }
            } else {
#pragma unroll
                for (int st = 0; st < 4; st++) {
                    float p[4];
#pragma unroll
                    for (int r = 0; r < 4; r++) {
                        p[r] = __builtin_exp2f(sa[st][r]);
                        ls += p[r];
                    }
                    pk[st * 2 + 0] = pkbf(p[0], p[1]);
                    pk[st * 2 + 1] = pkbf(p[2], p[3]);
                }
            }
            ls += __shfl_xor(ls, 16);
            ls += __shfl_xor(ls, 32);
            l_i += ls;
        }

        // ---- PV: ctx^T += V^T * P^T (shuffle-built P^T B-frags) ----
#pragma unroll
        for (int c = 0; c < 2; c++) {
            bf16x8 vf[4];
#pragma unroll
            for (int nt = 0; nt < 4; nt++)
                vf[nt] = *(const bf16x8*)&Vt[buf][SWZ(nt * 16 + l15, 4 * c + quad)];
            unsigned int a0 = __shfl((int)pk[4 * c + 0], srcA);
            unsigned int a1 = __shfl((int)pk[4 * c + 1], srcA);
            unsigned int a2 = __shfl((int)pk[4 * c + 0], srcB);
            unsigned int a3 = __shfl((int)pk[4 * c + 1], srcB);
            unsigned int b0 = __shfl((int)pk[4 * c + 2], srcA);
            unsigned int b1 = __shfl((int)pk[4 * c + 3], srcA);
            unsigned int b2 = __shfl((int)pk[4 * c + 2], srcB);
            unsigned int b3 = __shfl((int)pk[4 * c + 3], srcB);
            union { unsigned int u[4]; bf16x8 v; } pf;
            pf.u[0] = hi ? b0 : a0;
            pf.u[1] = hi ? b1 : a1;
            pf.u[2] = hi ? b2 : a2;
            pf.u[3] = hi ? b3 : a3;
#pragma unroll
            for (int nt = 0; nt < 4; nt++)
                acc[nt] = __builtin_amdgcn_mfma_f32_16x16x32_bf16(vf[nt], pf.v, acc[nt], 0, 0, 0);
        }
    }

    const int b = bh >> 4, h = bh & 15;
    const int q = t * 64 + wv * 16 + l15;
    const float inv = 1.0f / l_i;
#pragma unroll
    for (int nt = 0; nt < 4; nt++) {
        uint2 st2;
        st2.x = pkbf(acc[nt][0] * inv, acc[nt][1] * inv);
        st2.y = pkbf(acc[nt][2] * inv, acc[nt][3] * inv);
        *(uint2*)&CTX[((size_t)(b * S_LEN + q)) * D_MODEL + h * HDIM + nt * 16 + quad * 4] = st2;
    }
}

// ---------------- output projection: fp32 out = ctx @ Wo^T + bo --------------
__global__ __launch_bounds__(256) void outproj_kernel(
    const __hip_bfloat16* __restrict__ X, const __hip_bfloat16* __restrict__ W,
    const float* __restrict__ bias, float* __restrict__ OUT) {
    __shared__ __hip_bfloat16 As[128 * 32];
    __shared__ __hip_bfloat16 Bs[128 * 32];
    f32x4 acc[4][4];
#pragma unroll
    for (int i = 0; i < 4; i++)
#pragma unroll
        for (int j = 0; j < 4; j++) acc[i][j] = (f32x4){0.f, 0.f, 0.f, 0.f};
    const int m0 = blockIdx.x * 128, n0 = blockIdx.y * 128;
    gemm_mainloop(X, W, As, Bs, m0, n0, acc);
    const int tid = threadIdx.x;
    const int wv = tid >> 6, lane = tid & 63, l15 = lane & 15, quad = lane >> 4;
    const int rw = (wv >> 1) * 64, cw = (wv & 1) * 64;
#pragma unroll
    for (int mt = 0; mt < 4; mt++)
#pragma unroll
        for (int r = 0; r < 4; r++) {
            int m = m0 + rw + mt * 16 + quad * 4 + r;
#pragma unroll
            for (int nt = 0; nt < 4; nt++) {
                int n = n0 + cw + nt * 16 + l15;
                OUT[(size_t)m * D_MODEL + n] = acc[mt][nt][r] + bias[n];
            }
        }
}

extern "C" void kernel_launch(void* const* d_in, const int* in_sizes, int n_in,
                              void* d_out, int out_size, void* d_ws, size_t ws_size,
                              hipStream_t stream) {
    const float* x  = (const float*)d_in[0];
    const float* rc = (const float*)d_in[2];
    const float* rs = (const float*)d_in[3];
    const float* Wq = (const float*)d_in[4];
    const float* bq = (const float*)d_in[5];
    const float* Wk = (const float*)d_in[6];
    const float* bk = (const float*)d_in[7];
    const float* Wv = (const float*)d_in[8];
    const float* bv = (const float*)d_in[9];
    const float* Wo = (const float*)d_in[10];
    const float* bo = (const float*)d_in[11];

    char* ws = (char*)d_ws;
    __hip_bfloat16* xbf = (__hip_bfloat16*)(ws);                    // 16 MB (dead after qkv)
    __hip_bfloat16* VTb = (__hip_bfloat16*)(ws);                    // reuse: V^T [B,H,hd,S]
    __hip_bfloat16* wqb = (__hip_bfloat16*)(ws + (16u << 20));      // 2 MB
    __hip_bfloat16* wkb = (__hip_bfloat16*)(ws + (18u << 20));
    __hip_bfloat16* wvb = (__hip_bfloat16*)(ws + (20u << 20));
    __hip_bfloat16* wob = (__hip_bfloat16*)(ws + (22u << 20));
    __hip_bfloat16* Qb  = (__hip_bfloat16*)(ws + (24u << 20));      // 16 MB
    __hip_bfloat16* Kb  = (__hip_bfloat16*)(ws + (40u << 20));
    __hip_bfloat16* Vb  = (__hip_bfloat16*)(ws + (56u << 20));      // V row-major
    __hip_bfloat16* Cb  = (__hip_bfloat16*)(ws + (72u << 20));      // 16 MB
    float* out = (float*)d_out;

    f2bf4_kernel<<<8192, 256, 0, stream>>>((const float4*)x, (__hip_bfloat162*)xbf, 2097152);
    f2bfw_kernel<<<dim3(1024, 4), 256, 0, stream>>>(
        (const float4*)Wq, (const float4*)Wk, (const float4*)Wv, (const float4*)Wo,
        (__hip_bfloat162*)wqb, (__hip_bfloat162*)wkb, (__hip_bfloat162*)wvb,
        (__hip_bfloat162*)wob);

    qkv_kernel<<<dim3(64, 8, 3), 256, 0, stream>>>(xbf, wqb, wkb, wvb, bq, bk, bv,
                                                   rc, rs, Qb, Kb, Vb);
    vt_kernel<<<dim3(64, 32), 256, 0, stream>>>(Vb, VTb);
    attn_kernel<<<dim3(64, 32), 256, 0, stream>>>(Qb, Kb, VTb, Cb);
    outproj_kernel<<<dim3(64, 8), 256, 0, stream>>>(Cb, wob, bo, out);
}